// Round 3
// baseline (507.839 us; speedup 1.0000x reference)
//
#include <hip/hip_runtime.h>
#include <cstdint>
#include <cstddef>

typedef __bf16 bf16_t;
typedef __bf16 bf16x8 __attribute__((ext_vector_type(8)));
typedef __bf16 bf16x4 __attribute__((ext_vector_type(4)));
typedef float  f32x4  __attribute__((ext_vector_type(4)));
typedef _Float16 f16_t;

#define DHW   25088
#define SCALE 0.17677669529663687f  /* 32^-0.5 */

__device__ inline f32x4 mfma16(bf16x8 a, bf16x8 b, f32x4 c) {
  return __builtin_amdgcn_mfma_f32_16x16x32_bf16(a, b, c, 0, 0, 0);
}

__device__ inline unsigned pkh(float a, float b) {
  unsigned short ua = __builtin_bit_cast(unsigned short, (f16_t)a);
  unsigned short ub = __builtin_bit_cast(unsigned short, (f16_t)b);
  return (unsigned)ua | ((unsigned)ub << 16);
}
__device__ inline float upklo(unsigned u) {
  return (float)__builtin_bit_cast(f16_t, (unsigned short)(u & 0xffffu));
}
__device__ inline float upkhi(unsigned u) {
  return (float)__builtin_bit_cast(f16_t, (unsigned short)(u >> 16));
}

// window-order row -> global (rolled) token row
__device__ inline size_t wrow_to_grow(int orow) {
  int win = orow / 98, tok = orow % 98;
  int b = win >> 8, wr = win & 255;
  int bd = wr >> 6, bh = (wr >> 3) & 7, bwi = wr & 7;
  int md = tok / 49, mh = (tok / 7) % 7, mw = tok % 7;
  int d = (bd * 2 + md + 1) & 7;
  int h = bh * 7 + mh + 3; if (h >= 56) h -= 56;
  int w = bwi * 7 + mw + 3; if (w >= 56) w -= 56;
  return (size_t)b * DHW + (size_t)((d * 56 + h) * 56 + w);
}

// ---------------- K0: weight cast + bias/mask table (merged) ----------
__global__ __launch_bounds__(256) void prep_all_kernel(
    const float* __restrict__ qkv_w, const float* __restrict__ proj_w,
    const float* __restrict__ fc1_w, const float* __restrict__ rel_bias,
    const float* __restrict__ mask,
    bf16_t* __restrict__ wq, bf16_t* __restrict__ wp, bf16_t* __restrict__ wf,
    bf16_t* __restrict__ bmr)
{
  int idx = blockIdx.x * 256 + threadIdx.x;
  if (idx < 110592) { wq[idx] = (bf16_t)qkv_w[idx]; return; }
  idx -= 110592;
  if (idx < 36864) { wp[idx] = (bf16_t)proj_w[idx]; return; }
  idx -= 36864;
  if (idx < 36864) { wf[idx] = (bf16_t)fc1_w[idx]; return; }
  idx -= 36864;
  if (idx >= 688128) return;
  int e    = idx & 31;
  int lane = (idx >> 5) & 63;
  int t2   = idx >> 11;
  int mt   = t2 % 7;
  int wh   = t2 / 7;
  int type = wh / 6, h = wh - type * 6;
  int winb = ((type & 4) ? 3 : 0) * 64 + ((type & 2) ? 7 : 0) * 8 + ((type & 1) ? 7 : 0);
  int g = lane >> 4, li = lane & 15;
  int nt2 = e >> 2, v = e & 3;
  int row = mt * 16 + g * 4 + v;
  int col = nt2 * 16 + li;
  float val = -1e30f;
  if (row < 98 && col < 98 && nt2 < 7) {
    int di = row / 49 - col / 49 + 1;
    int hi = (row / 7) % 7 - (col / 7) % 7 + 6;
    int wi = row % 7 - col % 7 + 6;
    int rid = di * 169 + hi * 13 + wi;
    val = mask[winb * 9604 + row * 98 + col] + rel_bias[rid * 6 + h];
  }
  bmr[idx] = (bf16_t)val;
}

// ---------------- K1: fused per-window block, head-pair streaming -----
// 896 thr = 14 waves (wm 0..6, wn 0..1), LDS 79.1K -> 2 blocks/CU.
// Per head-pair hp: QKV tiles (Q/K/V 64 cols) -> attention (head 2hp+wn),
// attn-out kept as per-wave A-frags in regs; then frag-exchange -> proj -> fc1.
__global__ __launch_bounds__(896, 7) void fused_kernel(
    const float* __restrict__ x, const float* __restrict__ gw,
    const float* __restrict__ bw_, const bf16_t* __restrict__ wq,
    const float* __restrict__ qkv_b, const bf16_t* __restrict__ wp,
    const float* __restrict__ proj_b, const bf16_t* __restrict__ wf,
    const float* __restrict__ fc1_b, const bf16_t* __restrict__ bmr,
    float* __restrict__ out)
{
  __shared__ __align__(16) char smem[79104];
  bf16_t* U   = (bf16_t*)smem;                 // 25600: B-tile staging | PSc slots
  bf16_t* Qh  = (bf16_t*)(smem + 25600);       // 112x72
  bf16_t* Kh  = (bf16_t*)(smem + 41728);       // 112x72
  bf16_t* Vt  = (bf16_t*)(smem + 57856);       // 64x136 [d][tok]
  bf16_t* AoS = (bf16_t*)(smem + 25600);       // overlay: 42 frag dumps x 1KB
  bf16_t* C1  = (bf16_t*)(smem + 25600);       // overlay: 98x200
  float*  qb  = (float*)(smem + 75264);        // 576 f32 qkv bias -> pb -> fb
  float*  gwb = (float*)(smem + 77568);        // 384 f32 LN gamma/beta (persistent)

  #define BS(r, c)     U[(r) * 200 + (c)]
  #define PSc(w, r, c) U[(w) * 640 + (r) * 40 + (c)]
  #define QH(r, c)     Qh[(r) * 72 + (c)]
  #define KH(r, c)     Kh[(r) * 72 + (c)]
  #define VT(d, t)     Vt[(d) * 136 + (t)]
  #define C1M(r, c)    C1[(r) * 200 + (c)]

  int win  = blockIdx.x;
  int winb = win & 255;
  int type = (((winb >> 6) == 3) ? 4 : 0) | ((((winb >> 3) & 7) == 7) ? 2 : 0)
           | (((winb & 7) == 7) ? 1 : 0);
  int tid  = threadIdx.x;
  int wid  = tid >> 6, lane = tid & 63;
  int wn = wid & 1, wm = wid >> 1;
  int g = lane >> 4, li = lane & 15;

  if (tid < 192) { gwb[tid] = gw[tid]; gwb[192 + tid] = bw_[tid]; }
  if (tid < 576) qb[tid] = qkv_b[tid];
  {
    uint4 z = {0u, 0u, 0u, 0u};
    for (int c = tid; c < 1088; c += 896) ((uint4*)Vt)[c] = z;   // zero Vt (pads persist)
  }

  // ---- LN stats (mu/rstd kept; A-frags rebuilt per head-pair) ----
  int r = wm * 16 + li;
  const float* xr = nullptr;
  if (r < 98) {
    size_t growr = wrow_to_grow(win * 98 + r);
    xr = x + growr * 192 + g * 8;
  }
  float mu, rstd;
  {
    float s = 0.f, sq = 0.f;
    if (xr) {
      #pragma unroll
      for (int ks = 0; ks < 6; ks++) {
        float4 a = *(const float4*)(xr + ks * 32);
        float4 b = *(const float4*)(xr + ks * 32 + 4);
        s += a.x + a.y + a.z + a.w + b.x + b.y + b.z + b.w;
        sq += a.x*a.x + a.y*a.y + a.z*a.z + a.w*a.w
            + b.x*b.x + b.y*b.y + b.z*b.z + b.w*b.w;
      }
    }
    s += __shfl_xor(s, 16, 64); sq += __shfl_xor(sq, 16, 64);
    s += __shfl_xor(s, 32, 64); sq += __shfl_xor(sq, 32, 64);
    mu = s * (1.0f / 192.0f);
    float var = sq * (1.0f / 192.0f) - mu * mu;
    rstd = rsqrtf(var + 1e-5f);
  }
  __syncthreads();   // gwb/qb/Vt-zero visible

  auto build_afr = [&](bf16x8* afr) {
    #pragma unroll
    for (int ks = 0; ks < 6; ks++) {
      bf16x8 t;
      if (xr) {
        int c0 = ks * 32 + g * 8;
        float4 a = *(const float4*)(xr + ks * 32);
        float4 b = *(const float4*)(xr + ks * 32 + 4);
        float4 ga = *(const float4*)&gwb[c0],      gb = *(const float4*)&gwb[c0 + 4];
        float4 ba = *(const float4*)&gwb[192 + c0], bb = *(const float4*)&gwb[192 + c0 + 4];
        t[0] = (bf16_t)((a.x - mu) * rstd * ga.x + ba.x);
        t[1] = (bf16_t)((a.y - mu) * rstd * ga.y + ba.y);
        t[2] = (bf16_t)((a.z - mu) * rstd * ga.z + ba.z);
        t[3] = (bf16_t)((a.w - mu) * rstd * ga.w + ba.w);
        t[4] = (bf16_t)((b.x - mu) * rstd * gb.x + bb.x);
        t[5] = (bf16_t)((b.y - mu) * rstd * gb.y + bb.y);
        t[6] = (bf16_t)((b.z - mu) * rstd * gb.z + bb.z);
        t[7] = (bf16_t)((b.w - mu) * rstd * gb.w + bb.w);
      } else {
        #pragma unroll
        for (int j = 0; j < 8; j++) t[j] = (bf16_t)0.0f;
      }
      afr[ks] = t;
    }
  };

  uint4 st[2];
  auto loadw = [&](const bf16_t* w, int tile) {
    #pragma unroll
    for (int i = 0; i < 2; i++) {
      int c = tid + 896 * i;
      if (c < 1536) {
        int rr = c / 24, ck = c % 24;
        st[i] = *(const uint4*)(w + (size_t)tile * 12288 + (size_t)rr * 192 + ck * 8);
      }
    }
  };
  auto storebs = [&]() {
    #pragma unroll
    for (int i = 0; i < 2; i++) {
      int c = tid + 896 * i;
      if (c < 1536) {
        int rr = c / 24, ck = c % 24;
        *(uint4*)&BS(rr, ck * 8) = st[i];
      }
    }
  };

  int rqc = (wm * 16 + li < 98) ? (wm * 16 + li) : 97;
  bf16x8 a2loc[3];

  loadw(wq, 0);
  #pragma unroll
  for (int hp = 0; hp < 3; hp++) {
    bf16x8 afr[6];
    build_afr(afr);
    for (int tp = 0; tp < 3; tp++) {        // Q, K, V tile (64 cols each)
      __syncthreads();                      // prev U readers done
      storebs();
      __syncthreads();
      if (tp < 2) loadw(wq, hp + 3 * (tp + 1));
      f32x4 acc[2] = {};
      #pragma unroll
      for (int ks = 0; ks < 6; ks++) {
        bf16x8 b0 = *(const bf16x8*)&BS((wn * 2 + 0) * 16 + li, ks * 32 + g * 8);
        bf16x8 b1 = *(const bf16x8*)&BS((wn * 2 + 1) * 16 + li, ks * 32 + g * 8);
        acc[0] = mfma16(afr[ks], b0, acc[0]);
        acc[1] = mfma16(afr[ks], b1, acc[1]);
      }
      #pragma unroll
      for (int nl = 0; nl < 2; nl++)
      #pragma unroll
      for (int vv = 0; vv < 4; vv++) {
        int row = wm * 16 + g * 4 + vv;
        if (row < 98) {
          int cl = (wn * 2 + nl) * 16 + li;
          float val = acc[nl][vv] + qb[tp * 192 + hp * 64 + cl];
          if (tp == 0)      QH(row, cl) = (bf16_t)(val * SCALE);
          else if (tp == 1) KH(row, cl) = (bf16_t)val;
          else              VT(cl, row) = (bf16_t)val;
        }
      }
    }
    __syncthreads();                        // Kh/Vt ready; U free for PSc

    // ---- attention: head h = 2hp + wn ----
    {
      int h = 2 * hp + wn, hl = wn * 32;
      const bf16_t* bmp = bmr + ((((size_t)(type * 6 + h)) * 7 + wm) * 64 + lane) * 32;
      bf16x8 af = *(const bf16x8*)&QH(rqc, hl + g * 8);
      unsigned lp[7][2];
      float mx0 = -3.0e38f, mx1 = -3.0e38f, mx2 = -3.0e38f, mx3 = -3.0e38f;
      #pragma unroll
      for (int nt2 = 0; nt2 < 7; nt2++) {
        int rk = nt2 * 16 + li;
        int rkc = rk < 98 ? rk : 97;
        bf16x8 kf = *(const bf16x8*)&KH(rkc, hl + g * 8);
        f32x4 z = {};
        f32x4 S = mfma16(af, kf, z);
        bf16x4 bm4 = *(const bf16x4*)(bmp + nt2 * 4);
        float l0 = S[0] + (float)bm4[0];
        float l1 = S[1] + (float)bm4[1];
        float l2 = S[2] + (float)bm4[2];
        float l3 = S[3] + (float)bm4[3];
        mx0 = fmaxf(mx0, l0); mx1 = fmaxf(mx1, l1);
        mx2 = fmaxf(mx2, l2); mx3 = fmaxf(mx3, l3);
        lp[nt2][0] = pkh(l0, l1);
        lp[nt2][1] = pkh(l2, l3);
      }
      #pragma unroll
      for (int off = 1; off < 16; off <<= 1) {
        mx0 = fmaxf(mx0, __shfl_xor(mx0, off, 64));
        mx1 = fmaxf(mx1, __shfl_xor(mx1, off, 64));
        mx2 = fmaxf(mx2, __shfl_xor(mx2, off, 64));
        mx3 = fmaxf(mx3, __shfl_xor(mx3, off, 64));
      }
      float se0 = 0.f, se1 = 0.f, se2 = 0.f, se3 = 0.f;
      #pragma unroll
      for (int nt2 = 0; nt2 < 7; nt2++) {
        float p0 = __expf(upklo(lp[nt2][0]) - mx0);
        float p1 = __expf(upkhi(lp[nt2][0]) - mx1);
        float p2 = __expf(upklo(lp[nt2][1]) - mx2);
        float p3 = __expf(upkhi(lp[nt2][1]) - mx3);
        se0 += p0; se1 += p1; se2 += p2; se3 += p3;
        lp[nt2][0] = pkh(p0, p1);
        lp[nt2][1] = pkh(p2, p3);
      }
      #pragma unroll
      for (int off = 1; off < 16; off <<= 1) {
        se0 += __shfl_xor(se0, off, 64); se1 += __shfl_xor(se1, off, 64);
        se2 += __shfl_xor(se2, off, 64); se3 += __shfl_xor(se3, off, 64);
      }
      float inv0 = 1.0f / se0, inv1 = 1.0f / se1;
      float inv2 = 1.0f / se2, inv3 = 1.0f / se3;
      f32x4 o0 = {}, o1 = {};
      #pragma unroll
      for (int ch = 0; ch < 4; ch++) {
        #pragma unroll
        for (int nl = 0; nl < 2; nl++) {
          int nt2 = ch * 2 + nl;
          if (nt2 < 7) {
            PSc(wid, g * 4 + 0, nl * 16 + li) = (bf16_t)(upklo(lp[nt2][0]) * inv0);
            PSc(wid, g * 4 + 1, nl * 16 + li) = (bf16_t)(upkhi(lp[nt2][0]) * inv1);
            PSc(wid, g * 4 + 2, nl * 16 + li) = (bf16_t)(upklo(lp[nt2][1]) * inv2);
            PSc(wid, g * 4 + 3, nl * 16 + li) = (bf16_t)(upkhi(lp[nt2][1]) * inv3);
          } else {
            PSc(wid, g * 4 + 0, nl * 16 + li) = (bf16_t)0.0f;
            PSc(wid, g * 4 + 1, nl * 16 + li) = (bf16_t)0.0f;
            PSc(wid, g * 4 + 2, nl * 16 + li) = (bf16_t)0.0f;
            PSc(wid, g * 4 + 3, nl * 16 + li) = (bf16_t)0.0f;
          }
        }
        bf16x8 pf = *(const bf16x8*)&PSc(wid, li, g * 8);
        bf16x8 v0 = *(const bf16x8*)&VT(hl + li, ch * 32 + g * 8);
        bf16x8 v1 = *(const bf16x8*)&VT(hl + 16 + li, ch * 32 + g * 8);
        o0 = mfma16(pf, v0, o0);
        o1 = mfma16(pf, v1, o1);
      }
      // transpose attn-out to A-frag layout via the (dead) P slot
      #pragma unroll
      for (int vv = 0; vv < 4; vv++) {
        PSc(wid, g * 4 + vv, li)      = (bf16_t)o0[vv];
        PSc(wid, g * 4 + vv, 16 + li) = (bf16_t)o1[vv];
      }
      a2loc[hp] = *(const bf16x8*)&PSc(wid, li, g * 8);
    }
    if (hp < 2) loadw(wq, hp + 1);
    else        loadw(wp, 0);
  }

  __syncthreads();                          // all attention LDS reads done
  // frag-dump attn-out (overlay on Qh/Kh/Vt region)
  #pragma unroll
  for (int hp = 0; hp < 3; hp++) {
    int ks = 2 * hp + wn;
    *(bf16x8*)(AoS + (size_t)(wm * 6 + ks) * 512 + lane * 8) = a2loc[hp];
  }
  if (tid < 192) qb[tid] = proj_b[tid];
  __syncthreads();                          // AoS + pb visible
  bf16x8 a2[6];
  #pragma unroll
  for (int ks = 0; ks < 6; ks++)
    a2[ks] = *(const bf16x8*)(AoS + (size_t)(wm * 6 + ks) * 512 + lane * 8);

  // ---- proj GEMM -> C1 (overlay) ----
  for (int tp = 0; tp < 3; tp++) {
    __syncthreads();                        // tp=0: a2 reads done -> C1 writes safe
    storebs();
    __syncthreads();
    if (tp < 2) loadw(wp, tp + 1);
    else        loadw(wf, 0);
    f32x4 acc[2] = {};
    #pragma unroll
    for (int ks = 0; ks < 6; ks++) {
      bf16x8 b0 = *(const bf16x8*)&BS((wn * 2 + 0) * 16 + li, ks * 32 + g * 8);
      bf16x8 b1 = *(const bf16x8*)&BS((wn * 2 + 1) * 16 + li, ks * 32 + g * 8);
      acc[0] = mfma16(a2[ks], b0, acc[0]);
      acc[1] = mfma16(a2[ks], b1, acc[1]);
    }
    #pragma unroll
    for (int nl = 0; nl < 2; nl++)
    #pragma unroll
    for (int vv = 0; vv < 4; vv++) {
      int row = wm * 16 + g * 4 + vv;
      if (row < 98) {
        int cl = tp * 64 + (wn * 2 + nl) * 16 + li;
        C1M(row, cl) = (bf16_t)(acc[nl][vv] + qb[cl]);
      }
    }
  }
  __syncthreads();                          // C1 complete (pb dead)

  bf16x8 a3[6];
  #pragma unroll
  for (int ks = 0; ks < 6; ks++)
    a3[ks] = *(const bf16x8*)&C1M(rqc, ks * 32 + g * 8);
  if (tid < 192) qb[tid] = fc1_b[tid];
  size_t growv[4];
  #pragma unroll
  for (int vv = 0; vv < 4; vv++) {
    int row = wm * 16 + g * 4 + vv;
    growv[vv] = (row < 98) ? wrow_to_grow(win * 98 + row) : (size_t)0;
  }

  // ---- fc1 GEMM + GELU + residual ----
  for (int tp = 0; tp < 3; tp++) {
    __syncthreads();
    storebs();
    __syncthreads();
    if (tp < 2) loadw(wf, tp + 1);
    f32x4 acc[2] = {};
    #pragma unroll
    for (int ks = 0; ks < 6; ks++) {
      bf16x8 b0 = *(const bf16x8*)&BS((wn * 2 + 0) * 16 + li, ks * 32 + g * 8);
      bf16x8 b1 = *(const bf16x8*)&BS((wn * 2 + 1) * 16 + li, ks * 32 + g * 8);
      acc[0] = mfma16(a3[ks], b0, acc[0]);
      acc[1] = mfma16(a3[ks], b1, acc[1]);
    }
    #pragma unroll
    for (int vv = 0; vv < 4; vv++) {
      int row = wm * 16 + g * 4 + vv;
      if (row < 98) {
        const float* xrr = x + growv[vv] * 192;
        float* op = out + growv[vv] * 192;
        #pragma unroll
        for (int nl = 0; nl < 2; nl++) {
          int cl = tp * 64 + (wn * 2 + nl) * 16 + li;
          float val = acc[nl][vv] + qb[cl];
          float ge = 0.5f * val * (1.0f + erff(val * 0.70710678118654752f));
          op[cl] = xrr[cl] + ge;
        }
      }
    }
  }
  #undef BS
  #undef PSc
  #undef QH
  #undef KH
  #undef VT
  #undef C1M
}

// ---------------- launch ----------------
extern "C" void kernel_launch(void* const* d_in, const int* in_sizes, int n_in,
                              void* d_out, int out_size, void* d_ws, size_t ws_size,
                              hipStream_t stream) {
  (void)in_sizes; (void)n_in; (void)out_size; (void)ws_size;
  const float* x         = (const float*)d_in[0];
  const float* attn_mask = (const float*)d_in[1];
  const float* n1g       = (const float*)d_in[2];
  const float* n1b       = (const float*)d_in[3];
  const float* qkv_w     = (const float*)d_in[4];
  const float* qkv_b     = (const float*)d_in[5];
  const float* rel_bias  = (const float*)d_in[6];
  const float* proj_w    = (const float*)d_in[7];
  const float* proj_b    = (const float*)d_in[8];
  const float* fc1_w     = (const float*)d_in[9];
  const float* fc1_b     = (const float*)d_in[10];
  float* out = (float*)d_out;

  char* ws = (char*)d_ws;
  size_t off = 0;
  auto alloc = [&](size_t bytes) -> char* {
    char* p = ws + off;
    off += (bytes + 255) & ~(size_t)255;
    return p;
  };
  bf16_t* wq  = (bf16_t*)alloc(110592 * 2);
  bf16_t* wp  = (bf16_t*)alloc(36864 * 2);
  bf16_t* wf  = (bf16_t*)alloc(36864 * 2);
  bf16_t* bmr = (bf16_t*)alloc((size_t)688128 * 2);

  prep_all_kernel<<<3408, 256, 0, stream>>>(qkv_w, proj_w, fc1_w, rel_bias,
                                            attn_mask, wq, wp, wf, bmr);
  fused_kernel<<<1024, 896, 0, stream>>>(x, n1g, n1b, wq, qkv_b, wp, proj_b,
                                         wf, fc1_b, bmr, out);
}